// Round 1
// baseline (242.085 us; speedup 1.0000x reference)
//
#include <hip/hip_runtime.h>
#include <hip/hip_bf16.h>
#include <math.h>

#define B_ 64
#define L_ 512
#define D_ 768
#define H_ 384
#define T_ 9
#define M_ (B_ * L_)   // 32768 rows

typedef __attribute__((ext_vector_type(8))) short short8;
typedef __attribute__((ext_vector_type(4))) float f32x4;

__device__ __forceinline__ unsigned short f2bf(float f) {
    unsigned u = __float_as_uint(f);
    u += 0x7FFFu + ((u >> 16) & 1u);   // RNE
    return (unsigned short)(u >> 16);
}

// packed f32x2 -> bf16x2 (v_cvt_pk_bf16_f32 on gfx950)
__device__ __forceinline__ unsigned pkbf2(float a, float b) {
    __hip_bfloat162 h = __float22bfloat162_rn(float2{a, b});
    return *(unsigned*)&h;
}

// tanh-form gelu as x * sigmoid(2*0.79788456*(x + 0.044715 x^3)) — 1 exp.
__device__ __forceinline__ float gelu_fast(float x) {
    float z2 = 1.5957691216f * x + 0.0713548162726f * x * x * x;
    return x / (1.f + __expf(-z2));
}

__device__ __forceinline__ float wredf(float v) {
#pragma unroll
    for (int m = 32; m >= 1; m >>= 1) v += __shfl_xor(v, m, 64);
    return v;
}

// pack 8 f32 -> bf16x8 fragment
__device__ __forceinline__ short8 pack8(f32x4 a, f32x4 b) {
    int4 v = {(int)pkbf2(a[0], a[1]), (int)pkbf2(a[2], a[3]),
              (int)pkbf2(b[0], b[1]), (int)pkbf2(b[2], b[3])};
    return *(short8*)&v;
}

// direct global->LDS 16B DMA (wave-uniform LDS base + lane*16, per-lane global src)
__device__ __forceinline__ void stage16(const float* g, void* l) {
    __builtin_amdgcn_global_load_lds(
        (const __attribute__((address_space(1))) void*)g,
        (__attribute__((address_space(3))) void*)l, 16, 0, 0);
}

// -----------------------------------------------------------------------------
// Kernel 0: fragment-ordered bf16 weights + zero d_out.
//   W1F[((nt*24 + kc)*64 + lane)*8 + j] = W1[kc*32 + q*8 + j][nt*16 + lm]
//   W2F[(kk*64 + lane)*8 + j]           = (lm<9) ? W2[kk*32 + q*8 + j][lm] : 0
// -----------------------------------------------------------------------------
__global__ __launch_bounds__(256) void prep_kernel(
    const float* __restrict__ W1, const float* __restrict__ W2,
    unsigned short* __restrict__ W1F, unsigned short* __restrict__ W2F,
    float* __restrict__ out)
{
    if (blockIdx.x == 0 && threadIdx.x == 0) out[0] = 0.f;
    const int g    = blockIdx.x * 4 + (threadIdx.x >> 6);
    const int lane = threadIdx.x & 63;
    const int lm   = lane & 15;
    const int q    = lane >> 4;
    if (g < 576) {                       // W1F: g = nt*24 + kc
        const int nt = g / 24;
        const int kc = g - nt * 24;
        const int n  = nt * 16 + lm;
        short8 v;
#pragma unroll
        for (int j = 0; j < 8; ++j)
            v[j] = (short)f2bf(W1[(size_t)(kc * 32 + q * 8 + j) * H_ + n]);
        *(short8*)(W1F + ((size_t)g * 64 + lane) * 8) = v;
    } else if (g < 588) {                // W2F: kk = g - 576
        const int kk = g - 576;
        short8 v;
#pragma unroll
        for (int j = 0; j < 8; ++j) {
            int k = kk * 32 + q * 8 + j;
            v[j] = (lm < 9) ? (short)f2bf(W2[(size_t)k * T_ + lm]) : (short)0;
        }
        *(short8*)(W2F + ((size_t)kk * 64 + lane) * 8) = v;
    }
}

// -----------------------------------------------------------------------------
// Kernel 1: partial emissions. Grid 2048 = 1024 row-blocks x 2 n-halves
// (blockIdx = rb + 1024*half so twins share an XCD for X L2/L3 locality).
// BM=32, BN=192, 256 thr, 4 waves (each: 2 m-tiles x 3 n-tiles = 6 MFMA/iter).
// X staged fp32 DIRECT to LDS via global_load_lds (16B), XOR-swizzled source
// (chunk c stored at c^(row&7)) so fragment ds_read_b128 is bank-uniform.
// 2-phase schedule: one vmcnt(0)+s_barrier per k-step; W1F fragments
// register-prefetched 1 iter ahead (drained for free by the vmcnt(0)).
// Epilogue: gelu -> Hs -> 6 MFMA vs W2F half -> em0 (+b2) or em1.
// -----------------------------------------------------------------------------
__global__ __launch_bounds__(256, 5) void emis_mfma_kernel(
    const float* __restrict__ X,             // [M_][768] fp32
    const unsigned short* __restrict__ W1F,
    const float* __restrict__ b1,
    const unsigned short* __restrict__ W2F,
    const float* __restrict__ b2,
    float* __restrict__ em0,                 // [M_][9] half-0 partials (+b2)
    float* __restrict__ em1)                 // [M_][9] half-1 partials
{
    // Hs[32*200] u16 (12.8 KB) aliased over As[2][32][32] f32 (8 KB).
    __shared__ __align__(16) unsigned short Hs[32 * 200];
    float* AsF = (float*)Hs;

    const int t    = threadIdx.x;
    const int lane = t & 63;
    const int w    = t >> 6;
    const int lm   = lane & 15;
    const int q    = lane >> 4;
    const int half = blockIdx.x >> 10;
    const int rb   = blockIdx.x & 1023;
    const int row0 = rb * 32;

    // staging: thread t stages global row sr, 16B chunk sc = (t&7) ^ (sr&7)
    // into linear LDS byte (buf*4096 + t*16)  [rule 21: pre-swizzled source]
    const int sr = t >> 3;                        // 0..31
    const int sc = (t & 7) ^ (sr & 7);
    const float* sp = X + (size_t)(row0 + sr) * D_ + sc * 4;
    char* l0 = (char*)Hs + w * 1024;              // wave-uniform LDS bases
    char* l1 = l0 + 4096;

    const int ntg0 = half * 12 + w * 3;           // first global n-tile of wave

    // fragment read: row r = mt*16+lm, chunk c' = (q*2+j) ^ (lm&7)
    const int e7  = lm & 7;
    const int co0 = (((q * 2 + 0) ^ e7) << 2);    // float offset of 16B chunk
    const int co1 = (((q * 2 + 1) ^ e7) << 2);

    f32x4 acc[2][3];
#pragma unroll
    for (int mt = 0; mt < 2; ++mt)
#pragma unroll
        for (int i = 0; i < 3; ++i) acc[mt][i] = (f32x4)0.f;

    // ---- prologue: stage tile 0, prefetch bb(0) ----
    stage16(sp, l0);
    short8 bb[3];
#pragma unroll
    for (int i = 0; i < 3; ++i)
        bb[i] = *(const short8*)(W1F + (((size_t)(ntg0 + i) * 24 + 0) * 64 + lane) * 8);
    asm volatile("s_waitcnt vmcnt(0)" ::: "memory");
    __builtin_amdgcn_s_barrier();

#pragma unroll
    for (int kc = 0; kc < 24; ++kc) {
        const int s = kc & 1;
        // issue next-tile DMA + next-iter B fragments first (overlap)
        if (kc < 23) stage16(sp + (kc + 1) * 32, s ? l0 : l1);
        short8 bbn[3];
        if (kc < 23) {
#pragma unroll
            for (int i = 0; i < 3; ++i)
                bbn[i] = *(const short8*)(W1F +
                    (((size_t)(ntg0 + i) * 24 + kc + 1) * 64 + lane) * 8);
        }
        // A fragments: swizzled fp32 reads -> cvt_pk -> bf16x8
        const float* fb = AsF + s * 1024;
        short8 af[2];
#pragma unroll
        for (int mt = 0; mt < 2; ++mt) {
            const float* rp = fb + (mt * 16 + lm) * 32;
            f32x4 a0 = *(const f32x4*)(rp + co0);
            f32x4 a1 = *(const f32x4*)(rp + co1);
            af[mt] = pack8(a0, a1);
        }
#pragma unroll
        for (int mt = 0; mt < 2; ++mt)
#pragma unroll
            for (int i = 0; i < 3; ++i)
                acc[mt][i] = __builtin_amdgcn_mfma_f32_16x16x32_bf16(
                    af[mt], bb[i], acc[mt][i], 0, 0, 0);
        if (kc < 23) {
#pragma unroll
            for (int i = 0; i < 3; ++i) bb[i] = bbn[i];
            asm volatile("s_waitcnt vmcnt(0)" ::: "memory");
            __builtin_amdgcn_s_barrier();
        }
    }
    __syncthreads();   // all reads of As done before Hs (alias) is written

    // ---- epilogue A: +b1, gelu -> Hs (local cols 0..192, stride 200) ----
#pragma unroll
    for (int i = 0; i < 3; ++i) {
        const int lc = w * 48 + i * 16 + lm;
        const float b1v = b1[half * 192 + lc];
#pragma unroll
        for (int mt = 0; mt < 2; ++mt)
#pragma unroll
            for (int r = 0; r < 4; ++r) {
                float h = gelu_fast(acc[mt][i][r] + b1v);
                Hs[(mt * 16 + q * 4 + r) * 200 + lc] = f2bf(h);
            }
    }
    __syncthreads();

    // ---- epilogue B: partial em = h_half @ W2_half via 6 MFMA (waves 0,1) ----
    if (w < 2) {
        f32x4 e = (f32x4)0.f;
#pragma unroll
        for (int kk = 0; kk < 6; ++kk) {
            short8 ah = *(const short8*)&Hs[(w * 16 + lm) * 200 + kk * 32 + (q << 3)];
            short8 bw = *(const short8*)(W2F + ((size_t)((half * 6 + kk) * 64 + lane)) * 8);
            e = __builtin_amdgcn_mfma_f32_16x16x32_bf16(ah, bw, e, 0, 0, 0);
        }
        if (lm < 9) {
            float* emo = half ? em1 : em0;
            const float badd = half ? 0.f : b2[lm];
#pragma unroll
            for (int r = 0; r < 4; ++r)
                emo[(size_t)(row0 + w * 16 + q * 4 + r) * T_ + lm] = e[r] + badd;
        }
    }
}

// -----------------------------------------------------------------------------
// Kernel 2: CRF. 64 blocks x 640 threads.
// Phase A: threads 0..575 = (chunk c in [0,64), row i0) build 9x9 transfer
// matrices over 8 steps, trans in registers. Wave 9 (576..639) concurrently
// computes the numerator. Phase B: 6-level TREE combine of the 64 matrices
// (log-semiring matmul is associative). Final: alpha0 x M_total, logsumexp,
// atomicAdd of (denom-numer)/B into d_out (zeroed by prep).
// -----------------------------------------------------------------------------
__global__ __launch_bounds__(640) void crf_kernel(
    const float* __restrict__ em0,
    const float* __restrict__ em1,
    const int* __restrict__ labels,
    const unsigned char* __restrict__ maskb,
    const float* __restrict__ st,
    const float* __restrict__ et,
    const float* __restrict__ tr,
    float* __restrict__ out)
{
    const int b = blockIdx.x;
    const int t = threadIdx.x;

    __shared__ float es[64 * 73];    // es[c*73 + s*9 + j]
    __shared__ float Msa[64 * 81];
    __shared__ float Msb[32 * 81];
    __shared__ float trs[81];
    __shared__ float red_num;
    __shared__ unsigned char msh[L_];
    __shared__ int lbs[L_];

    const int mstride =
        (maskb[0] != 0 && maskb[1] == 0 && maskb[2] == 0 && maskb[3] == 0) ? 4 : 1;

    const float* e0 = em0 + (size_t)b * L_ * T_;
    const float* e1 = em1 + (size_t)b * L_ * T_;
    for (int i = t; i < L_ * T_; i += 640) {
        int tt = i / T_, j = i - tt * T_;
        es[(tt >> 3) * 73 + (tt & 7) * 9 + j] = e0[i] + e1[i];
    }
    if (t < 81) trs[t] = tr[t];
    for (int i = t; i < L_; i += 640) {
        msh[i] = maskb[((size_t)b * L_ + i) * (size_t)mstride];
        lbs[i] = labels[b * L_ + i];
    }
    __syncthreads();

    if (t < 576) {
        // ---- Phase A ----
        const int c  = t / 9;
        const int i0 = t - c * 9;
        float trr[81];
#pragma unroll
        for (int i = 0; i < 81; ++i) trr[i] = trs[i];
        float V[9];
#pragma unroll
        for (int j = 0; j < 9; ++j) V[j] = (j == i0) ? 0.f : -1e30f;

        const int sbeg = (c == 0) ? 1 : 0;
        for (int s = sbeg; s < 8; ++s) {
            int tt = c * 8 + s;
            if (msh[tt]) {
                const float* ep = &es[c * 73 + s * 9];
                float nv[9];
#pragma unroll
                for (int j = 0; j < 9; ++j) {
                    float a[9];
#pragma unroll
                    for (int k = 0; k < 9; ++k) a[k] = V[k] + trr[k * 9 + j];
                    float mx = a[0];
#pragma unroll
                    for (int k = 1; k < 9; ++k) mx = fmaxf(mx, a[k]);
                    float sum = 0.f;
#pragma unroll
                    for (int k = 0; k < 9; ++k) sum += __expf(a[k] - mx);
                    nv[j] = ep[j] + mx + __logf(sum);
                }
#pragma unroll
                for (int j = 0; j < 9; ++j) V[j] = nv[j];
            }
        }
#pragma unroll
        for (int j = 0; j < 9; ++j) Msa[c * 81 + i0 * 9 + j] = V[j];
    } else {
        // ---- numerator (wave 9, concurrent with Phase A) ----
        const int lane = t - 576;
        float emit_s = 0.f, tr_sc = 0.f, mcnt = 0.f;
        for (int tt = lane; tt < L_; tt += 64) {
            if (msh[tt]) {
                mcnt += 1.f;
                int tag = lbs[tt];
                emit_s += es[(tt >> 3) * 73 + (tt & 7) * 9 + tag];
                if (tt >= 1) tr_sc += trs[lbs[tt - 1] * 9 + tag];
            }
        }
        emit_s = wredf(emit_s);
        tr_sc  = wredf(tr_sc);
        mcnt   = wredf(mcnt);
        if (lane == 0) {
            int last = (int)mcnt - 1;
            red_num = st[lbs[0]] + emit_s + tr_sc + et[lbs[last]];
        }
    }
    __syncthreads();

    // ---- Phase B: tree combine, 6 levels ----
    float* src = Msa;
    float* dst = Msb;
    for (int n = 32; n >= 1; n >>= 1) {
        for (int idx = t; idx < n * 81; idx += 640) {
            int p = idx / 81;
            int r = idx - p * 81;
            int i = r / 9, j = r - i * 9;
            const float* A  = src + (2 * p) * 81 + i * 9;
            const float* Bm = src + (2 * p + 1) * 81 + j;
            float v[9];
#pragma unroll
            for (int k = 0; k < 9; ++k) v[k] = A[k] + Bm[k * 9];
            float mx = v[0];
#pragma unroll
            for (int k = 1; k < 9; ++k) mx = fmaxf(mx, v[k]);
            float sum = 0.f;
#pragma unroll
            for (int k = 0; k < 9; ++k) sum += __expf(v[k] - mx);
            dst[p * 81 + r] = mx + __logf(sum);
        }
        __syncthreads();
        float* tmp = src; src = dst; dst = tmp;
    }
    // final matrix in src (= Msa after 6 swaps)

    if (t < 64) {
        float v = -3.0e38f;
        if (t < 9) {
            float a[9];
#pragma unroll
            for (int i = 0; i < 9; ++i) a[i] = st[i] + es[i] + src[i * 9 + t];
            float mx = a[0];
#pragma unroll
            for (int i = 1; i < 9; ++i) mx = fmaxf(mx, a[i]);
            float sum = 0.f;
#pragma unroll
            for (int i = 0; i < 9; ++i) sum += __expf(a[i] - mx);
            v = mx + __logf(sum) + et[t];
        }
        float mx = v;
#pragma unroll
        for (int m = 32; m >= 1; m >>= 1) mx = fmaxf(mx, __shfl_xor(mx, m, 64));
        float sm = __expf(v - mx);
        sm = wredf(sm);
        if (t == 0) {
            float denom = mx + __logf(sm);
            atomicAdd(out, (denom - red_num) * (1.0f / (float)B_));
        }
    }
}

extern "C" void kernel_launch(void* const* d_in, const int* in_sizes, int n_in,
                              void* d_out, int out_size, void* d_ws, size_t ws_size,
                              hipStream_t stream) {
    const float*         enc    = (const float*)d_in[0];
    const int*           labels = (const int*)d_in[1];
    const unsigned char* mask   = (const unsigned char*)d_in[2];
    const float*         W1     = (const float*)d_in[3];
    const float*         b1     = (const float*)d_in[4];
    const float*         W2     = (const float*)d_in[5];
    const float*         b2     = (const float*)d_in[6];
    const float*         st     = (const float*)d_in[7];
    const float*         et     = (const float*)d_in[8];
    const float*         tr     = (const float*)d_in[9];

    float* em0          = (float*)d_ws;                        // 1,179,648 B
    float* em1          = em0 + (size_t)M_ * T_;               // 1,179,648 B
    unsigned short* W1F = (unsigned short*)(em1 + (size_t)M_ * T_);  // 589,824 B
    unsigned short* W2F = W1F + (size_t)576 * 64 * 8;          // 12,288 B

    prep_kernel<<<147, 256, 0, stream>>>(W1, W2, W1F, W2F, (float*)d_out);
    emis_mfma_kernel<<<2048, 256, 0, stream>>>(enc, W1F, b1, W2F, b2, em0, em1);
    crf_kernel<<<B_, 640, 0, stream>>>(em0, em1, labels, mask, st, et, tr, (float*)d_out);
}

// Round 2
// 237.619 us; speedup vs baseline: 1.0188x; 1.0188x over previous
//
#include <hip/hip_runtime.h>
#include <hip/hip_bf16.h>
#include <math.h>

#define B_ 64
#define L_ 512
#define D_ 768
#define H_ 384
#define T_ 9
#define M_ (B_ * L_)   // 32768 rows

typedef __attribute__((ext_vector_type(8))) short short8;
typedef __attribute__((ext_vector_type(4))) float f32x4;

__device__ __forceinline__ unsigned short f2bf(float f) {
    unsigned u = __float_as_uint(f);
    u += 0x7FFFu + ((u >> 16) & 1u);   // RNE
    return (unsigned short)(u >> 16);
}

// packed f32x2 -> bf16x2 (v_cvt_pk_bf16_f32 on gfx950)
__device__ __forceinline__ unsigned pkbf2(float a, float b) {
    __hip_bfloat162 h = __float22bfloat162_rn(float2{a, b});
    return *(unsigned*)&h;
}

// tanh-form gelu as x * sigmoid(2*0.79788456*(x + 0.044715 x^3)) — 1 exp.
__device__ __forceinline__ float gelu_fast(float x) {
    float z2 = 1.5957691216f * x + 0.0713548162726f * x * x * x;
    return x / (1.f + __expf(-z2));
}

__device__ __forceinline__ float wredf(float v) {
#pragma unroll
    for (int m = 32; m >= 1; m >>= 1) v += __shfl_xor(v, m, 64);
    return v;
}

// pack 8 f32 -> bf16x8 fragment
__device__ __forceinline__ short8 pack8(f32x4 a, f32x4 b) {
    int4 v = {(int)pkbf2(a[0], a[1]), (int)pkbf2(a[2], a[3]),
              (int)pkbf2(b[0], b[1]), (int)pkbf2(b[2], b[3])};
    return *(short8*)&v;
}

// direct global->LDS 16B DMA (wave-uniform LDS base + lane*16, per-lane global src)
__device__ __forceinline__ void stage16(const float* g, void* l) {
    __builtin_amdgcn_global_load_lds(
        (const __attribute__((address_space(1))) void*)g,
        (__attribute__((address_space(3))) void*)l, 16, 0, 0);
}

#define SBAR() __builtin_amdgcn_sched_barrier(0)

// -----------------------------------------------------------------------------
// Kernel 0: fragment-ordered bf16 weights + zero d_out.
//   W1F[((nt*24 + kc)*64 + lane)*8 + j] = W1[kc*32 + q*8 + j][nt*16 + lm]
//   W2F[(kk*64 + lane)*8 + j]           = (lm<9) ? W2[kk*32 + q*8 + j][lm] : 0
// -----------------------------------------------------------------------------
__global__ __launch_bounds__(256) void prep_kernel(
    const float* __restrict__ W1, const float* __restrict__ W2,
    unsigned short* __restrict__ W1F, unsigned short* __restrict__ W2F,
    float* __restrict__ out)
{
    if (blockIdx.x == 0 && threadIdx.x == 0) out[0] = 0.f;
    const int g    = blockIdx.x * 4 + (threadIdx.x >> 6);
    const int lane = threadIdx.x & 63;
    const int lm   = lane & 15;
    const int q    = lane >> 4;
    if (g < 576) {                       // W1F: g = nt*24 + kc
        const int nt = g / 24;
        const int kc = g - nt * 24;
        const int n  = nt * 16 + lm;
        short8 v;
#pragma unroll
        for (int j = 0; j < 8; ++j)
            v[j] = (short)f2bf(W1[(size_t)(kc * 32 + q * 8 + j) * H_ + n]);
        *(short8*)(W1F + ((size_t)g * 64 + lane) * 8) = v;
    } else if (g < 588) {                // W2F: kk = g - 576
        const int kk = g - 576;
        short8 v;
#pragma unroll
        for (int j = 0; j < 8; ++j) {
            int k = kk * 32 + q * 8 + j;
            v[j] = (lm < 9) ? (short)f2bf(W2[(size_t)k * T_ + lm]) : (short)0;
        }
        *(short8*)(W2F + ((size_t)kk * 64 + lane) * 8) = v;
    }
}

// -----------------------------------------------------------------------------
// Kernel 1: partial emissions. Grid 1024 = 512 row-blocks x 2 n-halves
// (blockIdx = rb + 512*half; 512%8==0 so twins share an XCD for X L2 reuse).
// BM=64, BN=192, 256 thr, 4 waves (each: 4 m-tiles x 3 n-tiles = 12 MFMA/iter).
// T3+T4 pipeline: 4 LDS tile buffers (8 KB each), X DMA'd DIRECT to LDS
// (global_load_lds 16B, XOR-swizzled source per rule 21) with depth-3
// prefetch; W1F fragments register-prefetched depth-2. One COUNTED
// s_waitcnt vmcnt(7) + s_barrier per k-step — per wave each iter issues
// exactly [3x W1F b128, then 2x stage] (order pinned by sched_barrier),
// so vmcnt(7) drains exactly {stage(kc)x2, bb(kc)x3}; 3 future half-tiles
// + 2 future B-fragment groups stay in flight across the barrier.
// Epilogue: gelu -> Hs (aliases staging LDS after vmcnt(0) drain) ->
// 6 MFMA vs W2F half -> em0 (+b2) or em1.
// -----------------------------------------------------------------------------
__global__ __launch_bounds__(256, 4) void emis_mfma_kernel(
    const float* __restrict__ X,             // [M_][768] fp32
    const unsigned short* __restrict__ W1F,
    const float* __restrict__ b1,
    const unsigned short* __restrict__ W2F,
    const float* __restrict__ b2,
    float* __restrict__ em0,                 // [M_][9] half-0 partials (+b2)
    float* __restrict__ em1)                 // [M_][9] half-1 partials
{
    // As[4][64][32] f32 tile buffers (32 KB); Hs[64][200] u16 (25.6 KB) aliases.
    __shared__ __align__(16) char smem[32768];
    unsigned short* Hs = (unsigned short*)smem;

    const int t    = threadIdx.x;
    const int lane = t & 63;
    const int w    = t >> 6;
    const int lm   = lane & 15;
    const int q    = lane >> 4;
    const int half = blockIdx.x >> 9;
    const int rb   = blockIdx.x & 511;
    const int row0 = rb * 64;

    // staging: thread t covers rows r0=t>>3 (call0) and r0+32 (call1),
    // 16B chunk-slot t&7, source chunk c = (t&7)^(r0&7)  [(r0+32)&7 == r0&7]
    const int r0 = t >> 3;
    const int c  = (t & 7) ^ (r0 & 7);
    const float* sp  = X + (size_t)(row0 + r0) * D_ + c * 4;
    const float* sp1 = sp + (size_t)32 * D_;

    const int ntg0 = half * 12 + w * 3;           // first global n-tile of wave

    // fragment read: row r = mt*16+lm, chunk c' = (2q+j) ^ (lm&7)  [r&7==lm&7]
    const int e7  = lm & 7;
    const int co0 = (((q * 2 + 0) ^ e7) << 2);    // float offset of 16B chunk
    const int co1 = (((q * 2 + 1) ^ e7) << 2);

    f32x4 acc[4][3];
#pragma unroll
    for (int mt = 0; mt < 4; ++mt)
#pragma unroll
        for (int i = 0; i < 3; ++i) acc[mt][i] = (f32x4)0.f;

    short8 bb[3][3];   // rotating B-fragment slots, all indices compile-time

    // ---- prologue: FIFO = [stage0 x2, bb0 x3 | stage1 x2, bb1 x3 | stage2 x2]
    stage16(sp,       smem + 0     + w * 1024);
    stage16(sp1,      smem + 4096  + w * 1024);
#pragma unroll
    for (int i = 0; i < 3; ++i)
        bb[0][i] = *(const short8*)(W1F + (((size_t)(ntg0 + i) * 24 + 0) * 64 + lane) * 8);
    SBAR();
    stage16(sp + 32,  smem + 8192  + w * 1024);
    stage16(sp1 + 32, smem + 12288 + w * 1024);
#pragma unroll
    for (int i = 0; i < 3; ++i)
        bb[1][i] = *(const short8*)(W1F + (((size_t)(ntg0 + i) * 24 + 1) * 64 + lane) * 8);
    SBAR();
    stage16(sp + 64,  smem + 16384 + w * 1024);
    stage16(sp1 + 64, smem + 20480 + w * 1024);
    SBAR();

#pragma unroll
    for (int kc = 0; kc < 24; ++kc) {
        const int cb = kc & 3;
        // counted wait: drains exactly {stage(kc)x2, bb(kc)x3}; 7 newer stay
        asm volatile("s_waitcnt vmcnt(7)\n\ts_barrier" ::: "memory");
        SBAR();
        // issue bb(kc+2) then stage(kc+3)  (clamped at tail to keep counts uniform)
        {
            const int kb = (kc + 2 <= 23) ? kc + 2 : 23;
#pragma unroll
            for (int i = 0; i < 3; ++i)
                bb[(kc + 2) % 3][i] = *(const short8*)(W1F +
                    (((size_t)(ntg0 + i) * 24 + kb) * 64 + lane) * 8);
        }
        SBAR();
        {
            const int ks = (kc + 3 <= 23) ? kc + 3 : 23;
            const int sb = (kc + 3) & 3;
            stage16(sp  + ks * 32, smem + sb * 8192        + w * 1024);
            stage16(sp1 + ks * 32, smem + sb * 8192 + 4096 + w * 1024);
        }
        SBAR();
        // A fragments: swizzled fp32 reads -> cvt_pk -> bf16x8, then 12 MFMA
        const float* fb = (const float*)(smem + cb * 8192);
        short8 af[4];
#pragma unroll
        for (int mt = 0; mt < 4; ++mt) {
            const float* rp = fb + (mt * 16 + lm) * 32;
            f32x4 a0 = *(const f32x4*)(rp + co0);
            f32x4 a1 = *(const f32x4*)(rp + co1);
            af[mt] = pack8(a0, a1);
        }
#pragma unroll
        for (int mt = 0; mt < 4; ++mt)
#pragma unroll
            for (int i = 0; i < 3; ++i)
                acc[mt][i] = __builtin_amdgcn_mfma_f32_16x16x32_bf16(
                    af[mt], bb[kc % 3][i], acc[mt][i], 0, 0, 0);
    }
    // drain leftover (redundant tail) DMAs before Hs overwrites the buffers
    asm volatile("s_waitcnt vmcnt(0)" ::: "memory");
    __syncthreads();

    // ---- epilogue A: +b1, gelu -> Hs (local cols 0..192, stride 200) ----
#pragma unroll
    for (int i = 0; i < 3; ++i) {
        const int lc = w * 48 + i * 16 + lm;
        const float b1v = b1[half * 192 + lc];
#pragma unroll
        for (int mt = 0; mt < 4; ++mt)
#pragma unroll
            for (int r = 0; r < 4; ++r) {
                float h = gelu_fast(acc[mt][i][r] + b1v);
                Hs[(mt * 16 + q * 4 + r) * 200 + lc] = f2bf(h);
            }
    }
    __syncthreads();

    // ---- epilogue B: partial em = h_half @ W2_half via 6 MFMA ----
    f32x4 e = (f32x4)0.f;
#pragma unroll
    for (int kk = 0; kk < 6; ++kk) {
        short8 ah = *(const short8*)&Hs[(w * 16 + lm) * 200 + kk * 32 + (q << 3)];
        short8 bw = *(const short8*)(W2F + ((size_t)((half * 6 + kk) * 64 + lane)) * 8);
        e = __builtin_amdgcn_mfma_f32_16x16x32_bf16(ah, bw, e, 0, 0, 0);
    }
    if (lm < 9) {
        float* emo = half ? em1 : em0;
        const float badd = half ? 0.f : b2[lm];
#pragma unroll
        for (int r = 0; r < 4; ++r)
            emo[(size_t)(row0 + w * 16 + q * 4 + r) * T_ + lm] = e[r] + badd;
    }
}

// -----------------------------------------------------------------------------
// Kernel 2: CRF. 64 blocks x 640 threads.
// Phase A: threads 0..575 = (chunk c in [0,64), row i0) build 9x9 transfer
// matrices over 8 steps, trans in registers. Wave 9 (576..639) concurrently
// computes the numerator. Phase B: 6-level TREE combine of the 64 matrices
// (log-semiring matmul is associative). Final: alpha0 x M_total, logsumexp,
// atomicAdd of (denom-numer)/B into d_out (zeroed by prep).
// -----------------------------------------------------------------------------
__global__ __launch_bounds__(640) void crf_kernel(
    const float* __restrict__ em0,
    const float* __restrict__ em1,
    const int* __restrict__ labels,
    const unsigned char* __restrict__ maskb,
    const float* __restrict__ st,
    const float* __restrict__ et,
    const float* __restrict__ tr,
    float* __restrict__ out)
{
    const int b = blockIdx.x;
    const int t = threadIdx.x;

    __shared__ float es[64 * 73];    // es[c*73 + s*9 + j]
    __shared__ float Msa[64 * 81];
    __shared__ float Msb[32 * 81];
    __shared__ float trs[81];
    __shared__ float red_num;
    __shared__ unsigned char msh[L_];
    __shared__ int lbs[L_];

    const int mstride =
        (maskb[0] != 0 && maskb[1] == 0 && maskb[2] == 0 && maskb[3] == 0) ? 4 : 1;

    const float* e0 = em0 + (size_t)b * L_ * T_;
    const float* e1 = em1 + (size_t)b * L_ * T_;
    for (int i = t; i < L_ * T_; i += 640) {
        int tt = i / T_, j = i - tt * T_;
        es[(tt >> 3) * 73 + (tt & 7) * 9 + j] = e0[i] + e1[i];
    }
    if (t < 81) trs[t] = tr[t];
    for (int i = t; i < L_; i += 640) {
        msh[i] = maskb[((size_t)b * L_ + i) * (size_t)mstride];
        lbs[i] = labels[b * L_ + i];
    }
    __syncthreads();

    if (t < 576) {
        // ---- Phase A ----
        const int c  = t / 9;
        const int i0 = t - c * 9;
        float trr[81];
#pragma unroll
        for (int i = 0; i < 81; ++i) trr[i] = trs[i];
        float V[9];
#pragma unroll
        for (int j = 0; j < 9; ++j) V[j] = (j == i0) ? 0.f : -1e30f;

        const int sbeg = (c == 0) ? 1 : 0;
        for (int s = sbeg; s < 8; ++s) {
            int tt = c * 8 + s;
            if (msh[tt]) {
                const float* ep = &es[c * 73 + s * 9];
                float nv[9];
#pragma unroll
                for (int j = 0; j < 9; ++j) {
                    float a[9];
#pragma unroll
                    for (int k = 0; k < 9; ++k) a[k] = V[k] + trr[k * 9 + j];
                    float mx = a[0];
#pragma unroll
                    for (int k = 1; k < 9; ++k) mx = fmaxf(mx, a[k]);
                    float sum = 0.f;
#pragma unroll
                    for (int k = 0; k < 9; ++k) sum += __expf(a[k] - mx);
                    nv[j] = ep[j] + mx + __logf(sum);
                }
#pragma unroll
                for (int j = 0; j < 9; ++j) V[j] = nv[j];
            }
        }
#pragma unroll
        for (int j = 0; j < 9; ++j) Msa[c * 81 + i0 * 9 + j] = V[j];
    } else {
        // ---- numerator (wave 9, concurrent with Phase A) ----
        const int lane = t - 576;
        float emit_s = 0.f, tr_sc = 0.f, mcnt = 0.f;
        for (int tt = lane; tt < L_; tt += 64) {
            if (msh[tt]) {
                mcnt += 1.f;
                int tag = lbs[tt];
                emit_s += es[(tt >> 3) * 73 + (tt & 7) * 9 + tag];
                if (tt >= 1) tr_sc += trs[lbs[tt - 1] * 9 + tag];
            }
        }
        emit_s = wredf(emit_s);
        tr_sc  = wredf(tr_sc);
        mcnt   = wredf(mcnt);
        if (lane == 0) {
            int last = (int)mcnt - 1;
            red_num = st[lbs[0]] + emit_s + tr_sc + et[lbs[last]];
        }
    }
    __syncthreads();

    // ---- Phase B: tree combine, 6 levels ----
    float* src = Msa;
    float* dst = Msb;
    for (int n = 32; n >= 1; n >>= 1) {
        for (int idx = t; idx < n * 81; idx += 640) {
            int p = idx / 81;
            int r = idx - p * 81;
            int i = r / 9, j = r - i * 9;
            const float* A  = src + (2 * p) * 81 + i * 9;
            const float* Bm = src + (2 * p + 1) * 81 + j;
            float v[9];
#pragma unroll
            for (int k = 0; k < 9; ++k) v[k] = A[k] + Bm[k * 9];
            float mx = v[0];
#pragma unroll
            for (int k = 1; k < 9; ++k) mx = fmaxf(mx, v[k]);
            float sum = 0.f;
#pragma unroll
            for (int k = 0; k < 9; ++k) sum += __expf(v[k] - mx);
            dst[p * 81 + r] = mx + __logf(sum);
        }
        __syncthreads();
        float* tmp = src; src = dst; dst = tmp;
    }
    // final matrix in src (= Msa after 6 swaps)

    if (t < 64) {
        float v = -3.0e38f;
        if (t < 9) {
            float a[9];
#pragma unroll
            for (int i = 0; i < 9; ++i) a[i] = st[i] + es[i] + src[i * 9 + t];
            float mx = a[0];
#pragma unroll
            for (int i = 1; i < 9; ++i) mx = fmaxf(mx, a[i]);
            float sum = 0.f;
#pragma unroll
            for (int i = 0; i < 9; ++i) sum += __expf(a[i] - mx);
            v = mx + __logf(sum) + et[t];
        }
        float mx = v;
#pragma unroll
        for (int m = 32; m >= 1; m >>= 1) mx = fmaxf(mx, __shfl_xor(mx, m, 64));
        float sm = __expf(v - mx);
        sm = wredf(sm);
        if (t == 0) {
            float denom = mx + __logf(sm);
            atomicAdd(out, (denom - red_num) * (1.0f / (float)B_));
        }
    }
}

extern "C" void kernel_launch(void* const* d_in, const int* in_sizes, int n_in,
                              void* d_out, int out_size, void* d_ws, size_t ws_size,
                              hipStream_t stream) {
    const float*         enc    = (const float*)d_in[0];
    const int*           labels = (const int*)d_in[1];
    const unsigned char* mask   = (const unsigned char*)d_in[2];
    const float*         W1     = (const float*)d_in[3];
    const float*         b1     = (const float*)d_in[4];
    const float*         W2     = (const float*)d_in[5];
    const float*         b2     = (const float*)d_in[6];
    const float*         st     = (const float*)d_in[7];
    const float*         et     = (const float*)d_in[8];
    const float*         tr     = (const float*)d_in[9];

    float* em0          = (float*)d_ws;                        // 1,179,648 B
    float* em1          = em0 + (size_t)M_ * T_;               // 1,179,648 B
    unsigned short* W1F = (unsigned short*)(em1 + (size_t)M_ * T_);  // 589,824 B
    unsigned short* W2F = W1F + (size_t)576 * 64 * 8;          // 12,288 B

    prep_kernel<<<147, 256, 0, stream>>>(W1, W2, W1F, W2F, (float*)d_out);
    emis_mfma_kernel<<<1024, 256, 0, stream>>>(enc, W1F, b1, W2F, b2, em0, em1);
    crf_kernel<<<B_, 640, 0, stream>>>(em0, em1, labels, mask, st, et, tr, (float*)d_out);
}

// Round 3
// 228.468 us; speedup vs baseline: 1.0596x; 1.0401x over previous
//
#include <hip/hip_runtime.h>
#include <hip/hip_bf16.h>
#include <math.h>

#define B_ 64
#define L_ 512
#define D_ 768
#define H_ 384
#define T_ 9
#define M_ (B_ * L_)   // 32768 rows

typedef __attribute__((ext_vector_type(8))) short short8;
typedef __attribute__((ext_vector_type(4))) float f32x4;

__device__ __forceinline__ unsigned short f2bf(float f) {
    unsigned u = __float_as_uint(f);
    u += 0x7FFFu + ((u >> 16) & 1u);   // RNE
    return (unsigned short)(u >> 16);
}

// packed f32x2 -> bf16x2 (v_cvt_pk_bf16_f32 on gfx950)
__device__ __forceinline__ unsigned pkbf2(float a, float b) {
    __hip_bfloat162 h = __float22bfloat162_rn(float2{a, b});
    return *(unsigned*)&h;
}

// tanh-form gelu as x * sigmoid(2*0.79788456*(x + 0.044715 x^3)) — 1 exp.
__device__ __forceinline__ float gelu_fast(float x) {
    float z2 = 1.5957691216f * x + 0.0713548162726f * x * x * x;
    return x / (1.f + __expf(-z2));
}

__device__ __forceinline__ float wredf(float v) {
#pragma unroll
    for (int m = 32; m >= 1; m >>= 1) v += __shfl_xor(v, m, 64);
    return v;
}

// pack 8 f32 -> bf16x8 fragment
__device__ __forceinline__ short8 pack8(f32x4 a, f32x4 b) {
    int4 v = {(int)pkbf2(a[0], a[1]), (int)pkbf2(a[2], a[3]),
              (int)pkbf2(b[0], b[1]), (int)pkbf2(b[2], b[3])};
    return *(short8*)&v;
}

// direct global->LDS 16B DMA (wave-uniform LDS base + lane*16, per-lane global src)
__device__ __forceinline__ void stage16(const float* g, void* l) {
    __builtin_amdgcn_global_load_lds(
        (const __attribute__((address_space(1))) void*)g,
        (__attribute__((address_space(3))) void*)l, 16, 0, 0);
}

// swizzled A-fragment load: row mt*16+lm, two XOR'd 16B chunks -> bf16x8
__device__ __forceinline__ short8 ldfrag(const float* fb, int mt, int lm,
                                         int co0, int co1) {
    const float* rp = fb + (mt * 16 + lm) * 32;
    f32x4 a0 = *(const f32x4*)(rp + co0);
    f32x4 a1 = *(const f32x4*)(rp + co1);
    return pack8(a0, a1);
}

// -----------------------------------------------------------------------------
// Kernel 0: fragment-ordered bf16 weights + zero d_out.
//   W1F[((nt*24 + kc)*64 + lane)*8 + j] = W1[kc*32 + q*8 + j][nt*16 + lm]
//   W2F[(kk*64 + lane)*8 + j]           = (lm<9) ? W2[kk*32 + q*8 + j][lm] : 0
// -----------------------------------------------------------------------------
__global__ __launch_bounds__(256) void prep_kernel(
    const float* __restrict__ W1, const float* __restrict__ W2,
    unsigned short* __restrict__ W1F, unsigned short* __restrict__ W2F,
    float* __restrict__ out)
{
    if (blockIdx.x == 0 && threadIdx.x == 0) out[0] = 0.f;
    const int g    = blockIdx.x * 4 + (threadIdx.x >> 6);
    const int lane = threadIdx.x & 63;
    const int lm   = lane & 15;
    const int q    = lane >> 4;
    if (g < 576) {                       // W1F: g = nt*24 + kc
        const int nt = g / 24;
        const int kc = g - nt * 24;
        const int n  = nt * 16 + lm;
        short8 v;
#pragma unroll
        for (int j = 0; j < 8; ++j)
            v[j] = (short)f2bf(W1[(size_t)(kc * 32 + q * 8 + j) * H_ + n]);
        *(short8*)(W1F + ((size_t)g * 64 + lane) * 8) = v;
    } else if (g < 588) {                // W2F: kk = g - 576
        const int kk = g - 576;
        short8 v;
#pragma unroll
        for (int j = 0; j < 8; ++j) {
            int k = kk * 32 + q * 8 + j;
            v[j] = (lm < 9) ? (short)f2bf(W2[(size_t)k * T_ + lm]) : (short)0;
        }
        *(short8*)(W2F + ((size_t)kk * 64 + lane) * 8) = v;
    }
}

// -----------------------------------------------------------------------------
// Kernel 1: partial emissions. Grid 1024 = 512 row-blocks x 2 n-halves.
// BM=64, BN=192, 256 thr, 4 waves (each: 4 m-tiles x 3 n-tiles = 12 MFMA/iter).
// T3+T4 pipeline with GUARANTEED-STATIC register indexing (rule #20): the
// k-loop is manually unrolled via macro with literal indices; B-fragment
// triple-buffer is three NAMED arrays (bbs0/1/2) picked by token paste —
// nothing can spill to scratch (round-2 bug: WRITE_SIZE 2.3->20.7 MB,
// VGPR_Count 64 => bb[] rotation went to scratch).
// Depth-3 LDS tile prefetch (4 x 8 KB), bb depth-2, one counted
// s_waitcnt vmcnt(7)+s_barrier per k-step (tail: exact literal waits 5, 0;
// no clamped redundant loads).
// -----------------------------------------------------------------------------
__global__ __launch_bounds__(256, 3) void emis_mfma_kernel(
    const float* __restrict__ X,             // [M_][768] fp32
    const unsigned short* __restrict__ W1F,
    const float* __restrict__ b1,
    const unsigned short* __restrict__ W2F,
    const float* __restrict__ b2,
    float* __restrict__ em0,                 // [M_][9] half-0 partials (+b2)
    float* __restrict__ em1)                 // [M_][9] half-1 partials
{
    // As[4][64][32] f32 tile buffers (32 KB); Hs[64][200] u16 (25.6 KB) aliases.
    __shared__ __align__(16) char smem[32768];
    unsigned short* Hs = (unsigned short*)smem;

    const int t    = threadIdx.x;
    const int lane = t & 63;
    const int w    = t >> 6;
    const int lm   = lane & 15;
    const int q    = lane >> 4;
    const int half = blockIdx.x >> 9;
    const int rb   = blockIdx.x & 511;
    const int row0 = rb * 64;

    // staging: thread t covers rows r0=t>>3 (call0) and r0+32 (call1),
    // 16B chunk-slot t&7, source chunk c = (t&7)^(r0&7)  [(r0+32)&7 == r0&7]
    const int r0 = t >> 3;
    const int c  = (t & 7) ^ (r0 & 7);
    const float* sp  = X + (size_t)(row0 + r0) * D_ + c * 4;
    const float* sp1 = sp + (size_t)32 * D_;

    const int ntg0 = half * 12 + w * 3;           // first global n-tile of wave

    // fragment read: row r = mt*16+lm, chunk c' = (2q+j) ^ (lm&7)  [r&7==lm&7]
    const int e7  = lm & 7;
    const int co0 = (((q * 2 + 0) ^ e7) << 2);    // float offset of 16B chunk
    const int co1 = (((q * 2 + 1) ^ e7) << 2);

    f32x4 acc[4][3];
#pragma unroll
    for (int mt = 0; mt < 4; ++mt)
#pragma unroll
        for (int i = 0; i < 3; ++i) acc[mt][i] = (f32x4)0.f;

    // named B-fragment buffers — literal indexing only (no scratch)
    short8 bbs0[3], bbs1[3], bbs2[3];

#define BB_(s) bbs##s
#define LOADBB(dst, kc)                                                          \
    do {                                                                         \
        dst[0] = *(const short8*)(W1F + (((size_t)(ntg0 + 0) * 24 + (kc)) * 64 + lane) * 8); \
        dst[1] = *(const short8*)(W1F + (((size_t)(ntg0 + 1) * 24 + (kc)) * 64 + lane) * 8); \
        dst[2] = *(const short8*)(W1F + (((size_t)(ntg0 + 2) * 24 + (kc)) * 64 + lane) * 8); \
    } while (0)

    // ---- prologue: FIFO = [stage0 x2, bb0 x3 | stage1 x2, bb1 x3 | stage2 x2]
    stage16(sp,       smem + 0     + w * 1024);
    stage16(sp1,      smem + 4096  + w * 1024);
    LOADBB(bbs0, 0);
    __builtin_amdgcn_sched_barrier(0);
    stage16(sp + 32,  smem + 8192  + w * 1024);
    stage16(sp1 + 32, smem + 12288 + w * 1024);
    LOADBB(bbs1, 1);
    __builtin_amdgcn_sched_barrier(0);
    stage16(sp + 64,  smem + 16384 + w * 1024);
    stage16(sp1 + 64, smem + 20480 + w * 1024);
    __builtin_amdgcn_sched_barrier(0);

    // One k-step. KC literal; CUR = KC%3; P2 = (KC+2)%3; WN = exact wait count.
    // Wait drains exactly {stage(KC)x2, bb(KC)x3}; newer ops stay in flight.
#define KSTEP(KC, CUR, P2, WN)                                                   \
    do {                                                                         \
        asm volatile("s_waitcnt vmcnt(" #WN ")\n\ts_barrier" ::: "memory");      \
        __builtin_amdgcn_sched_barrier(0);                                       \
        if ((KC) + 2 <= 23) { LOADBB(BB_(P2), (KC) + 2); }                       \
        __builtin_amdgcn_sched_barrier(0);                                       \
        if ((KC) + 3 <= 23) {                                                    \
            stage16(sp  + ((KC) + 3) * 32, smem + (((KC) + 3) & 3) * 8192        + w * 1024); \
            stage16(sp1 + ((KC) + 3) * 32, smem + (((KC) + 3) & 3) * 8192 + 4096 + w * 1024); \
        }                                                                        \
        __builtin_amdgcn_sched_barrier(0);                                       \
        {                                                                        \
            const float* fb = (const float*)(smem + ((KC) & 3) * 8192);          \
            short8 af0 = ldfrag(fb, 0, lm, co0, co1);                            \
            short8 af1 = ldfrag(fb, 1, lm, co0, co1);                            \
            short8 af2 = ldfrag(fb, 2, lm, co0, co1);                            \
            short8 af3 = ldfrag(fb, 3, lm, co0, co1);                            \
            acc[0][0] = __builtin_amdgcn_mfma_f32_16x16x32_bf16(af0, BB_(CUR)[0], acc[0][0], 0, 0, 0); \
            acc[0][1] = __builtin_amdgcn_mfma_f32_16x16x32_bf16(af0, BB_(CUR)[1], acc[0][1], 0, 0, 0); \
            acc[0][2] = __builtin_amdgcn_mfma_f32_16x16x32_bf16(af0, BB_(CUR)[2], acc[0][2], 0, 0, 0); \
            acc[1][0] = __builtin_amdgcn_mfma_f32_16x16x32_bf16(af1, BB_(CUR)[0], acc[1][0], 0, 0, 0); \
            acc[1][1] = __builtin_amdgcn_mfma_f32_16x16x32_bf16(af1, BB_(CUR)[1], acc[1][1], 0, 0, 0); \
            acc[1][2] = __builtin_amdgcn_mfma_f32_16x16x32_bf16(af1, BB_(CUR)[2], acc[1][2], 0, 0, 0); \
            acc[2][0] = __builtin_amdgcn_mfma_f32_16x16x32_bf16(af2, BB_(CUR)[0], acc[2][0], 0, 0, 0); \
            acc[2][1] = __builtin_amdgcn_mfma_f32_16x16x32_bf16(af2, BB_(CUR)[1], acc[2][1], 0, 0, 0); \
            acc[2][2] = __builtin_amdgcn_mfma_f32_16x16x32_bf16(af2, BB_(CUR)[2], acc[2][2], 0, 0, 0); \
            acc[3][0] = __builtin_amdgcn_mfma_f32_16x16x32_bf16(af3, BB_(CUR)[0], acc[3][0], 0, 0, 0); \
            acc[3][1] = __builtin_amdgcn_mfma_f32_16x16x32_bf16(af3, BB_(CUR)[1], acc[3][1], 0, 0, 0); \
            acc[3][2] = __builtin_amdgcn_mfma_f32_16x16x32_bf16(af3, BB_(CUR)[2], acc[3][2], 0, 0, 0); \
        }                                                                        \
    } while (0)

    KSTEP(0, 0, 2, 7);   KSTEP(1, 1, 0, 7);   KSTEP(2, 2, 1, 7);
    KSTEP(3, 0, 2, 7);   KSTEP(4, 1, 0, 7);   KSTEP(5, 2, 1, 7);
    KSTEP(6, 0, 2, 7);   KSTEP(7, 1, 0, 7);   KSTEP(8, 2, 1, 7);
    KSTEP(9, 0, 2, 7);   KSTEP(10, 1, 0, 7);  KSTEP(11, 2, 1, 7);
    KSTEP(12, 0, 2, 7);  KSTEP(13, 1, 0, 7);  KSTEP(14, 2, 1, 7);
    KSTEP(15, 0, 2, 7);  KSTEP(16, 1, 0, 7);  KSTEP(17, 2, 1, 7);
    KSTEP(18, 0, 2, 7);  KSTEP(19, 1, 0, 7);  KSTEP(20, 2, 1, 7);
    KSTEP(21, 0, 2, 7);  KSTEP(22, 1, 0, 5);  KSTEP(23, 2, 1, 0);

#undef KSTEP
#undef LOADBB
#undef BB_

    __syncthreads();   // all reads of As done before Hs (alias) is written

    // ---- epilogue A: +b1, gelu -> Hs (local cols 0..192, stride 200) ----
#pragma unroll
    for (int i = 0; i < 3; ++i) {
        const int lc = w * 48 + i * 16 + lm;
        const float b1v = b1[half * 192 + lc];
#pragma unroll
        for (int mt = 0; mt < 4; ++mt)
#pragma unroll
            for (int r = 0; r < 4; ++r) {
                float h = gelu_fast(acc[mt][i][r] + b1v);
                Hs[(mt * 16 + q * 4 + r) * 200 + lc] = f2bf(h);
            }
    }
    __syncthreads();

    // ---- epilogue B: partial em = h_half @ W2_half via 6 MFMA ----
    f32x4 e = (f32x4)0.f;
#pragma unroll
    for (int kk = 0; kk < 6; ++kk) {
        short8 ah = *(const short8*)&Hs[(w * 16 + lm) * 200 + kk * 32 + (q << 3)];
        short8 bw = *(const short8*)(W2F + ((size_t)((half * 6 + kk) * 64 + lane)) * 8);
        e = __builtin_amdgcn_mfma_f32_16x16x32_bf16(ah, bw, e, 0, 0, 0);
    }
    if (lm < 9) {
        float* emo = half ? em1 : em0;
        const float badd = half ? 0.f : b2[lm];
#pragma unroll
        for (int r = 0; r < 4; ++r)
            emo[(size_t)(row0 + w * 16 + q * 4 + r) * T_ + lm] = e[r] + badd;
    }
}

// -----------------------------------------------------------------------------
// Kernel 2: CRF. 64 blocks x 640 threads.
// Phase A: threads 0..575 = (chunk c in [0,64), row i0) build 9x9 transfer
// matrices over 8 steps, trans in registers. Wave 9 (576..639) concurrently
// computes the numerator. Phase B: 6-level TREE combine of the 64 matrices
// (log-semiring matmul is associative). Final: alpha0 x M_total, logsumexp,
// atomicAdd of (denom-numer)/B into d_out (zeroed by prep).
// -----------------------------------------------------------------------------
__global__ __launch_bounds__(640) void crf_kernel(
    const float* __restrict__ em0,
    const float* __restrict__ em1,
    const int* __restrict__ labels,
    const unsigned char* __restrict__ maskb,
    const float* __restrict__ st,
    const float* __restrict__ et,
    const float* __restrict__ tr,
    float* __restrict__ out)
{
    const int b = blockIdx.x;
    const int t = threadIdx.x;

    __shared__ float es[64 * 73];    // es[c*73 + s*9 + j]
    __shared__ float Msa[64 * 81];
    __shared__ float Msb[32 * 81];
    __shared__ float trs[81];
    __shared__ float red_num;
    __shared__ unsigned char msh[L_];
    __shared__ int lbs[L_];

    const int mstride =
        (maskb[0] != 0 && maskb[1] == 0 && maskb[2] == 0 && maskb[3] == 0) ? 4 : 1;

    const float* e0 = em0 + (size_t)b * L_ * T_;
    const float* e1 = em1 + (size_t)b * L_ * T_;
    for (int i = t; i < L_ * T_; i += 640) {
        int tt = i / T_, j = i - tt * T_;
        es[(tt >> 3) * 73 + (tt & 7) * 9 + j] = e0[i] + e1[i];
    }
    if (t < 81) trs[t] = tr[t];
    for (int i = t; i < L_; i += 640) {
        msh[i] = maskb[((size_t)b * L_ + i) * (size_t)mstride];
        lbs[i] = labels[b * L_ + i];
    }
    __syncthreads();

    if (t < 576) {
        // ---- Phase A ----
        const int c  = t / 9;
        const int i0 = t - c * 9;
        float trr[81];
#pragma unroll
        for (int i = 0; i < 81; ++i) trr[i] = trs[i];
        float V[9];
#pragma unroll
        for (int j = 0; j < 9; ++j) V[j] = (j == i0) ? 0.f : -1e30f;

        const int sbeg = (c == 0) ? 1 : 0;
        for (int s = sbeg; s < 8; ++s) {
            int tt = c * 8 + s;
            if (msh[tt]) {
                const float* ep = &es[c * 73 + s * 9];
                float nv[9];
#pragma unroll
                for (int j = 0; j < 9; ++j) {
                    float a[9];
#pragma unroll
                    for (int k = 0; k < 9; ++k) a[k] = V[k] + trr[k * 9 + j];
                    float mx = a[0];
#pragma unroll
                    for (int k = 1; k < 9; ++k) mx = fmaxf(mx, a[k]);
                    float sum = 0.f;
#pragma unroll
                    for (int k = 0; k < 9; ++k) sum += __expf(a[k] - mx);
                    nv[j] = ep[j] + mx + __logf(sum);
                }
#pragma unroll
                for (int j = 0; j < 9; ++j) V[j] = nv[j];
            }
        }
#pragma unroll
        for (int j = 0; j < 9; ++j) Msa[c * 81 + i0 * 9 + j] = V[j];
    } else {
        // ---- numerator (wave 9, concurrent with Phase A) ----
        const int lane = t - 576;
        float emit_s = 0.f, tr_sc = 0.f, mcnt = 0.f;
        for (int tt = lane; tt < L_; tt += 64) {
            if (msh[tt]) {
                mcnt += 1.f;
                int tag = lbs[tt];
                emit_s += es[(tt >> 3) * 73 + (tt & 7) * 9 + tag];
                if (tt >= 1) tr_sc += trs[lbs[tt - 1] * 9 + tag];
            }
        }
        emit_s = wredf(emit_s);
        tr_sc  = wredf(tr_sc);
        mcnt   = wredf(mcnt);
        if (lane == 0) {
            int last = (int)mcnt - 1;
            red_num = st[lbs[0]] + emit_s + tr_sc + et[lbs[last]];
        }
    }
    __syncthreads();

    // ---- Phase B: tree combine, 6 levels ----
    float* src = Msa;
    float* dst = Msb;
    for (int n = 32; n >= 1; n >>= 1) {
        for (int idx = t; idx < n * 81; idx += 640) {
            int p = idx / 81;
            int r = idx - p * 81;
            int i = r / 9, j = r - i * 9;
            const float* A  = src + (2 * p) * 81 + i * 9;
            const float* Bm = src + (2 * p + 1) * 81 + j;
            float v[9];
#pragma unroll
            for (int k = 0; k < 9; ++k) v[k] = A[k] + Bm[k * 9];
            float mx = v[0];
#pragma unroll
            for (int k = 1; k < 9; ++k) mx = fmaxf(mx, v[k]);
            float sum = 0.f;
#pragma unroll
            for (int k = 0; k < 9; ++k) sum += __expf(v[k] - mx);
            dst[p * 81 + r] = mx + __logf(sum);
        }
        __syncthreads();
        float* tmp = src; src = dst; dst = tmp;
    }
    // final matrix in src (= Msa after 6 swaps)

    if (t < 64) {
        float v = -3.0e38f;
        if (t < 9) {
            float a[9];
#pragma unroll
            for (int i = 0; i < 9; ++i) a[i] = st[i] + es[i] + src[i * 9 + t];
            float mx = a[0];
#pragma unroll
            for (int i = 1; i < 9; ++i) mx = fmaxf(mx, a[i]);
            float sum = 0.f;
#pragma unroll
            for (int i = 0; i < 9; ++i) sum += __expf(a[i] - mx);
            v = mx + __logf(sum) + et[t];
        }
        float mx = v;
#pragma unroll
        for (int m = 32; m >= 1; m >>= 1) mx = fmaxf(mx, __shfl_xor(mx, m, 64));
        float sm = __expf(v - mx);
        sm = wredf(sm);
        if (t == 0) {
            float denom = mx + __logf(sm);
            atomicAdd(out, (denom - red_num) * (1.0f / (float)B_));
        }
    }
}

extern "C" void kernel_launch(void* const* d_in, const int* in_sizes, int n_in,
                              void* d_out, int out_size, void* d_ws, size_t ws_size,
                              hipStream_t stream) {
    const float*         enc    = (const float*)d_in[0];
    const int*           labels = (const int*)d_in[1];
    const unsigned char* mask   = (const unsigned char*)d_in[2];
    const float*         W1     = (const float*)d_in[3];
    const float*         b1     = (const float*)d_in[4];
    const float*         W2     = (const float*)d_in[5];
    const float*         b2     = (const float*)d_in[6];
    const float*         st     = (const float*)d_in[7];
    const float*         et     = (const float*)d_in[8];
    const float*         tr     = (const float*)d_in[9];

    float* em0          = (float*)d_ws;                        // 1,179,648 B
    float* em1          = em0 + (size_t)M_ * T_;               // 1,179,648 B
    unsigned short* W1F = (unsigned short*)(em1 + (size_t)M_ * T_);  // 589,824 B
    unsigned short* W2F = W1F + (size_t)576 * 64 * 8;          // 12,288 B

    prep_kernel<<<147, 256, 0, stream>>>(W1, W2, W1F, W2F, (float*)d_out);
    emis_mfma_kernel<<<1024, 256, 0, stream>>>(enc, W1F, b1, W2F, b2, em0, em1);
    crf_kernel<<<B_, 640, 0, stream>>>(em0, em1, labels, mask, st, et, tr, (float*)d_out);
}